// Round 12
// baseline (139.086 us; speedup 1.0000x reference)
//
#include <hip/hip_runtime.h>

typedef __bf16 v8bf __attribute__((ext_vector_type(8)));
typedef float  v4f  __attribute__((ext_vector_type(4)));

#define D     512
#define NSUP  20
#define NC    64
#define RES   25
#define BB    128
#define LAM   (20.0f/512.0f)
#define KT    32
#define NKT   (D/KT)     // 16
#define CPB   8
#define COLS  160        // CPB*NSUP
#define FRAGSZ (16*D)    // ushorts per fragment-row-group (16 rows x 512 k)

__device__ __forceinline__ ushort bf_hi(float v) {
    uint32_t b = __float_as_uint(v);
    return (ushort)((b + 0x7FFF + ((b >> 16) & 1)) >> 16);   // RNE
}
__device__ __forceinline__ float us2f(ushort u) {
    return __uint_as_float(((uint32_t)u) << 16);
}
// fragment-linear address (in ushorts): row R, k index k
__device__ __forceinline__ int fl_addr(int R, int k) {
    return (R >> 4) * FRAGSZ + (k >> 3) * 128 + (R & 15) * 8 + (k & 7);
}

// ---- Kernel 1 (fused): [blocks 0..127] Gram + dual register-Cholesky +
// ---- panel solves -> fragment-linear Hth/Htl; [blocks 128..255] X hi/lo
// ---- split -> fragment-linear Xh/Xl (pad rows zeroed).
__global__ __launch_bounds__(256) void k_prep(const float* __restrict__ high,
                                              const float* __restrict__ x,
                                              ushort* __restrict__ Hth,
                                              ushort* __restrict__ Htl,
                                              ushort* __restrict__ Xh,
                                              ushort* __restrict__ Xl) {
    const int t = threadIdx.x;

    if (blockIdx.x >= 128) {               // ---- X split, 1 batch per block --
        const int batch = blockIdx.x - 128;
        // 32 rows x 64 octets = 2048 jobs, 8 per thread
        for (int idx = t; idx < 32 * 64; idx += 256) {
            int r = idx >> 6, o = idx & 63;        // row 0..31, k-octet 0..63
            v8bf hv = (v8bf)(__bf16)0.f, lv = hv;
            if (r < RES) {
                const float* p = &x[(batch * RES + r) * D + (o << 3)];
                float4 v0 = *(const float4*)p, v1 = *(const float4*)(p + 4);
                float vv[8] = {v0.x, v0.y, v0.z, v0.w, v1.x, v1.y, v1.z, v1.w};
                #pragma unroll
                for (int e = 0; e < 8; ++e) {
                    ushort h = bf_hi(vv[e]);
                    ((ushort*)&hv)[e] = h;
                    ((ushort*)&lv)[e] = bf_hi(vv[e] - us2f(h));
                }
            }
            int a = fl_addr(batch * 32 + r, o << 3);
            *(v8bf*)&Xh[a] = hv;
            *(v8bf*)&Xl[a] = lv;
        }
        return;
    }

    const int cls  = blockIdx.x >> 1;
    const int half = blockIdx.x & 1;
    __shared__ float Hc[NSUP * 516];
    __shared__ float Gs[NSUP * NSUP];
    __shared__ float Ls[400], Rs[400], rL[NSUP];

    for (int i = t; i < NSUP * (D / 4); i += 256) {
        int r = i >> 7, c4 = (i & 127) << 2;
        *(float4*)&Hc[r * 516 + c4] = *(const float4*)&high[(cls * NSUP + r) * D + c4];
    }
    __syncthreads();

    // Gram — symmetric half only
    for (int e = t; e < NSUP * NSUP; e += 256) {
        int i = e / NSUP, j = e % NSUP;
        if (i <= j) {
            float s = 0.f;
            for (int k = 0; k < D; k += 4) {
                float4 a = *(float4*)&Hc[i * 516 + k];
                float4 b = *(float4*)&Hc[j * 516 + k];
                s += a.x * b.x + a.y * b.y + a.z * b.z + a.w * b.w;
            }
            Gs[i * NSUP + j] = s;
            Gs[j * NSUP + i] = s;
        }
    }
    __syncthreads();

    // dual in-register Cholesky on wave 0 (lanes 0-19: B, 32-51: C2)
    if (t < 64) {
        const int c  = t & 31;
        const int gp = t >> 5;
        const float dlam = gp ? 2.0f * LAM : LAM;
        float m[NSUP];
        if (c < NSUP) {
            #pragma unroll
            for (int i = 0; i < NSUP; ++i) m[i] = Gs[i * NSUP + c];
            #pragma unroll
            for (int i = 0; i < NSUP; ++i) if (i == c) m[i] += dlam;
        }
        #pragma unroll
        for (int k = 0; k < NSUP; ++k) {
            float piv = __shfl(m[k], k, 32);     // M[k][k] from lane k
            float sq  = sqrtf(piv);
            float rsq = 1.0f / sq;
            float lck = m[k] * rsq;              // L[c][k] via symmetry (c>k)
            if (c == k) {
                m[k] = sq;
                #pragma unroll
                for (int i = k + 1; i < NSUP; ++i) m[i] *= rsq;
            }
            #pragma unroll
            for (int i = k + 1; i < NSUP; ++i) {
                float lik = __shfl(m[i], k, 32); // L[i][k] (post-scale)
                if (c > k) m[i] -= lik * lck;
            }
        }
        if (c < NSUP) {
            float* Lout = gp ? Rs : Ls;
            #pragma unroll
            for (int i = 0; i < NSUP; ++i) if (i >= c) Lout[i * NSUP + c] = m[i];
            if (!gp) rL[c] = 1.0f / m[c];
        }
    }
    __syncthreads();

    // panel solves for this block's 256 columns (H from LDS)
    const int col = half * 256 + t;
    float h[NSUP];
    #pragma unroll
    for (int m = 0; m < NSUP; ++m) h[m] = Hc[m * 516 + col];
    #pragma unroll
    for (int i = 0; i < NSUP; ++i) {            // forward: L z = h
        float s = h[i];
        #pragma unroll
        for (int m = 0; m < i; ++m) s -= Ls[i * NSUP + m] * h[m];
        h[i] = s * rL[i];
    }
    #pragma unroll
    for (int i = NSUP - 1; i >= 0; --i) {       // backward: L^T w = z
        float s = h[i];
        #pragma unroll
        for (int m = i + 1; m < NSUP; ++m) s -= Ls[m * NSUP + i] * h[m];
        h[i] = s * rL[i];
    }
    #pragma unroll
    for (int i = 0; i < NSUP; ++i) {            // ht = R^T w; hi/lo split
        float s = 0.f;
        #pragma unroll
        for (int m = i; m < NSUP; ++m) s += Rs[m * NSUP + i] * h[m];
        ushort hh = bf_hi(s);
        float  rr = s - us2f(hh);
        int a = fl_addr(cls * NSUP + i, col);
        Hth[a] = hh;
        Htl[a] = bf_hi(rr);
    }
}

// ---- Kernel 2: Z = X @ Htilde^T, all-register, fragment-linear operands ----
// grid (8 cg, 128 batches), 256 threads = 4 waves; wave = 1 M-frag x 5 N-frags.
// No barriers in the K loop; every A/B load is a contiguous 1KB instruction.
__global__ __launch_bounds__(256, 8) void k_main(const ushort* __restrict__ Xh,
                                                 const ushort* __restrict__ Xl,
                                                 const ushort* __restrict__ Hth,
                                                 const ushort* __restrict__ Htl,
                                                 float* __restrict__ S) {
    const int cg = blockIdx.x, batch = blockIdx.y;
    const int t = threadIdx.x, lane = t & 63, wid = t >> 6;
    const int wm = wid >> 1, wn = wid & 1;
    const int r16 = lane & 15, q = lane >> 4;

    __shared__ float colsum[2][COLS];

    v4f acc[5];
    #pragma unroll
    for (int b = 0; b < 5; ++b) acc[b] = (v4f){0.f, 0.f, 0.f, 0.f};

    const int abase = (batch * 2 + wm) * FRAGSZ + lane * 8;
    const ushort* ah_p = Xh + abase;
    const ushort* al_p = Xl + abase;
    const ushort* bh_p[5];
    const ushort* bl_p[5];
    #pragma unroll
    for (int nf = 0; nf < 5; ++nf) {
        int fb = (cg * 10 + wn * 5 + nf) * FRAGSZ + lane * 8;
        bh_p[nf] = Hth + fb;
        bl_p[nf] = Htl + fb;
    }

    for (int s = 0; s < NKT; ++s) {
        const int off = s * 512;
        v8bf ah = *(const v8bf*)(ah_p + off);
        v8bf al = *(const v8bf*)(al_p + off);
        #pragma unroll
        for (int nf = 0; nf < 5; ++nf) {
            v8bf bh = *(const v8bf*)(bh_p[nf] + off);
            v8bf bl = *(const v8bf*)(bl_p[nf] + off);
            // 3-pass: drop al*bl (<= 2^-18 relative)
            acc[nf] = __builtin_amdgcn_mfma_f32_16x16x32_bf16(ah, bh, acc[nf], 0, 0, 0);
            acc[nf] = __builtin_amdgcn_mfma_f32_16x16x32_bf16(ah, bl, acc[nf], 0, 0, 0);
            acc[nf] = __builtin_amdgcn_mfma_f32_16x16x32_bf16(al, bh, acc[nf], 0, 0, 0);
        }
    }

    // z^2 column sums; C-frag: col = lane&15, row = 4*(lane>>4)+j
    #pragma unroll
    for (int nf = 0; nf < 5; ++nf) {
        float part = 0.f;
        #pragma unroll
        for (int j = 0; j < 4; ++j) part += acc[nf][j] * acc[nf][j];
        part += __shfl_xor(part, 16);
        part += __shfl_xor(part, 32);
        if (q == 0) colsum[wm][wn * 80 + nf * 16 + r16] = part;
    }
    __syncthreads();
    if (t < CPB) {
        float s = 0.f;
        #pragma unroll
        for (int i = 0; i < NSUP; ++i)
            s += colsum[0][t * 20 + i] + colsum[1][t * 20 + i];
        S[batch * NC + cg * CPB + t] = s;
    }
}

// ---- Kernel 3: per-row min-max ----
__global__ __launch_bounds__(64) void k_minmax(const float* __restrict__ S,
                                               float* __restrict__ out) {
    const int b    = blockIdx.x;
    const int lane = threadIdx.x;
    float s  = S[b * NC + lane];
    float mn = s, mx = s;
    #pragma unroll
    for (int off = 32; off > 0; off >>= 1) {
        mn = fminf(mn, __shfl_xor(mn, off, 64));
        mx = fmaxf(mx, __shfl_xor(mx, off, 64));
    }
    out[b * NC + lane] = (s - mn) / (mx - mn);
}

extern "C" void kernel_launch(void* const* d_in, const int* in_sizes, int n_in,
                              void* d_out, int out_size, void* d_ws, size_t ws_size,
                              hipStream_t stream) {
    const float* x    = (const float*)d_in[0];
    const float* high = (const float*)d_in[1];
    float* out = (float*)d_out;

    ushort* Hth = (ushort*)d_ws;                   // 80 frags  * 8192 = 1.31 MB
    ushort* Htl = Hth + 80 * FRAGSZ;               // 1.31 MB
    ushort* Xh  = Htl + 80 * FRAGSZ;               // 256 frags * 8192 = 4.19 MB
    ushort* Xl  = Xh + 256 * FRAGSZ;               // 4.19 MB
    float*  S   = (float*)(Xl + 256 * FRAGSZ);     // 32 KB

    k_prep  <<<256, 256, 0, stream>>>(high, x, Hth, Htl, Xh, Xl);
    k_main  <<<dim3(CPB, BB), 256, 0, stream>>>(Xh, Xl, Hth, Htl, S);
    k_minmax<<<BB, 64, 0, stream>>>(S, out);
}

// Round 13
// 137.382 us; speedup vs baseline: 1.0124x; 1.0124x over previous
//
#include <hip/hip_runtime.h>

typedef __bf16 v8bf __attribute__((ext_vector_type(8)));
typedef float  v4f  __attribute__((ext_vector_type(4)));

#define D     512
#define NSUP  20
#define NC    64
#define RES   25
#define BB    128
#define LAM   (20.0f/512.0f)
#define KT    32
#define NKT   (D/KT)     // 16
#define CPB   8
#define COLS  160        // CPB*NSUP
#define FRAGSZ (16*D)    // ushorts per fragment-row-group (16 rows x 512 k)

__device__ __forceinline__ ushort bf_hi(float v) {
    uint32_t b = __float_as_uint(v);
    return (ushort)((b + 0x7FFF + ((b >> 16) & 1)) >> 16);   // RNE
}
__device__ __forceinline__ float us2f(ushort u) {
    return __uint_as_float(((uint32_t)u) << 16);
}
// fragment-linear address (in ushorts): row R, k index k
__device__ __forceinline__ int fl_addr(int R, int k) {
    return (R >> 4) * FRAGSZ + (k >> 3) * 128 + (R & 15) * 8 + (k & 7);
}

// ---- Kernel 1 (fused): [blocks 0..127] Gram + dual register-Cholesky +
// ---- panel solves -> fragment-linear Hth/Htl; [blocks 128..255] X hi/lo
// ---- split -> fragment-linear Xh/Xl (pad rows zeroed).
__global__ __launch_bounds__(256) void k_prep(const float* __restrict__ high,
                                              const float* __restrict__ x,
                                              ushort* __restrict__ Hth,
                                              ushort* __restrict__ Htl,
                                              ushort* __restrict__ Xh,
                                              ushort* __restrict__ Xl) {
    const int t = threadIdx.x;

    if (blockIdx.x >= 128) {               // ---- X split, 1 batch per block --
        const int batch = blockIdx.x - 128;
        for (int idx = t; idx < 32 * 64; idx += 256) {
            int r = idx >> 6, o = idx & 63;        // row 0..31, k-octet 0..63
            v8bf hv = (v8bf)(__bf16)0.f, lv = hv;
            if (r < RES) {
                const float* p = &x[(batch * RES + r) * D + (o << 3)];
                float4 v0 = *(const float4*)p, v1 = *(const float4*)(p + 4);
                float vv[8] = {v0.x, v0.y, v0.z, v0.w, v1.x, v1.y, v1.z, v1.w};
                #pragma unroll
                for (int e = 0; e < 8; ++e) {
                    ushort h = bf_hi(vv[e]);
                    ((ushort*)&hv)[e] = h;
                    ((ushort*)&lv)[e] = bf_hi(vv[e] - us2f(h));
                }
            }
            int a = fl_addr(batch * 32 + r, o << 3);
            *(v8bf*)&Xh[a] = hv;
            *(v8bf*)&Xl[a] = lv;
        }
        return;
    }

    const int cls  = blockIdx.x >> 1;
    const int half = blockIdx.x & 1;
    __shared__ float Hc[NSUP * 516];
    __shared__ float Gs[NSUP * NSUP];
    __shared__ float Ls[400], Rs[400], rL[NSUP];

    for (int i = t; i < NSUP * (D / 4); i += 256) {
        int r = i >> 7, c4 = (i & 127) << 2;
        *(float4*)&Hc[r * 516 + c4] = *(const float4*)&high[(cls * NSUP + r) * D + c4];
    }
    __syncthreads();

    // Gram — symmetric half only
    for (int e = t; e < NSUP * NSUP; e += 256) {
        int i = e / NSUP, j = e % NSUP;
        if (i <= j) {
            float s = 0.f;
            for (int k = 0; k < D; k += 4) {
                float4 a = *(float4*)&Hc[i * 516 + k];
                float4 b = *(float4*)&Hc[j * 516 + k];
                s += a.x * b.x + a.y * b.y + a.z * b.z + a.w * b.w;
            }
            Gs[i * NSUP + j] = s;
            Gs[j * NSUP + i] = s;
        }
    }
    __syncthreads();

    // dual in-register Cholesky on wave 0 (lanes 0-19: B, 32-51: C2)
    if (t < 64) {
        const int c  = t & 31;
        const int gp = t >> 5;
        const float dlam = gp ? 2.0f * LAM : LAM;
        float m[NSUP];
        if (c < NSUP) {
            #pragma unroll
            for (int i = 0; i < NSUP; ++i) m[i] = Gs[i * NSUP + c];
            #pragma unroll
            for (int i = 0; i < NSUP; ++i) if (i == c) m[i] += dlam;
        }
        #pragma unroll
        for (int k = 0; k < NSUP; ++k) {
            float piv = __shfl(m[k], k, 32);     // M[k][k] from lane k
            float sq  = sqrtf(piv);
            float rsq = 1.0f / sq;
            float lck = m[k] * rsq;              // L[c][k] via symmetry (c>k)
            if (c == k) {
                m[k] = sq;
                #pragma unroll
                for (int i = k + 1; i < NSUP; ++i) m[i] *= rsq;
            }
            #pragma unroll
            for (int i = k + 1; i < NSUP; ++i) {
                float lik = __shfl(m[i], k, 32); // L[i][k] (post-scale)
                if (c > k) m[i] -= lik * lck;
            }
        }
        if (c < NSUP) {
            float* Lout = gp ? Rs : Ls;
            #pragma unroll
            for (int i = 0; i < NSUP; ++i) if (i >= c) Lout[i * NSUP + c] = m[i];
            if (!gp) rL[c] = 1.0f / m[c];
        }
    }
    __syncthreads();

    // panel solves for this block's 256 columns (H from LDS)
    const int col = half * 256 + t;
    float h[NSUP];
    #pragma unroll
    for (int m = 0; m < NSUP; ++m) h[m] = Hc[m * 516 + col];
    #pragma unroll
    for (int i = 0; i < NSUP; ++i) {            // forward: L z = h
        float s = h[i];
        #pragma unroll
        for (int m = 0; m < i; ++m) s -= Ls[i * NSUP + m] * h[m];
        h[i] = s * rL[i];
    }
    #pragma unroll
    for (int i = NSUP - 1; i >= 0; --i) {       // backward: L^T w = z
        float s = h[i];
        #pragma unroll
        for (int m = i + 1; m < NSUP; ++m) s -= Ls[m * NSUP + i] * h[m];
        h[i] = s * rL[i];
    }
    #pragma unroll
    for (int i = 0; i < NSUP; ++i) {            // ht = R^T w; hi/lo split
        float s = 0.f;
        #pragma unroll
        for (int m = i; m < NSUP; ++m) s += Rs[m * NSUP + i] * h[m];
        ushort hh = bf_hi(s);
        float  rr = s - us2f(hh);
        int a = fl_addr(cls * NSUP + i, col);
        Hth[a] = hh;
        Htl[a] = bf_hi(rr);
    }
}

// ---- Kernel 2: Z = X @ Htilde^T, all-register, fragment-linear operands ----
// Flat 1024-block grid, XCD-locality swizzle (a=2 cg-halves, b=4 batch-quarters):
// xcd = bid&7 (round-robin heuristic); each XCD: X-quarter (2.1MB) stays L2-
// resident across 4 batch-major cg passes; H(cg) 0.65MB streamed per pass.
__global__ __launch_bounds__(256, 8) void k_main(const ushort* __restrict__ Xh,
                                                 const ushort* __restrict__ Xl,
                                                 const ushort* __restrict__ Hth,
                                                 const ushort* __restrict__ Htl,
                                                 float* __restrict__ S) {
    const int bid = blockIdx.x;
    const int xcd = bid & 7;
    const int j   = bid >> 3;                 // 0..127 within XCD
    const int cg    = (xcd >> 2) * 4 + (j >> 5);       // 0..7
    const int batch = (xcd & 3) * 32 + (j & 31);       // 0..127

    const int t = threadIdx.x, lane = t & 63, wid = t >> 6;
    const int wm = wid >> 1, wn = wid & 1;
    const int r16 = lane & 15, q = lane >> 4;

    __shared__ float colsum[2][COLS];

    v4f acc[5];
    #pragma unroll
    for (int b = 0; b < 5; ++b) acc[b] = (v4f){0.f, 0.f, 0.f, 0.f};

    const int abase = (batch * 2 + wm) * FRAGSZ + lane * 8;
    const ushort* ah_p = Xh + abase;
    const ushort* al_p = Xl + abase;
    const ushort* bh_p[5];
    const ushort* bl_p[5];
    #pragma unroll
    for (int nf = 0; nf < 5; ++nf) {
        int fb = (cg * 10 + wn * 5 + nf) * FRAGSZ + lane * 8;
        bh_p[nf] = Hth + fb;
        bl_p[nf] = Htl + fb;
    }

    for (int s = 0; s < NKT; ++s) {
        const int off = s * 512;
        v8bf ah = *(const v8bf*)(ah_p + off);
        v8bf al = *(const v8bf*)(al_p + off);
        #pragma unroll
        for (int nf = 0; nf < 5; ++nf) {
            v8bf bh = *(const v8bf*)(bh_p[nf] + off);
            v8bf bl = *(const v8bf*)(bl_p[nf] + off);
            // 3-pass: drop al*bl (<= 2^-18 relative)
            acc[nf] = __builtin_amdgcn_mfma_f32_16x16x32_bf16(ah, bh, acc[nf], 0, 0, 0);
            acc[nf] = __builtin_amdgcn_mfma_f32_16x16x32_bf16(ah, bl, acc[nf], 0, 0, 0);
            acc[nf] = __builtin_amdgcn_mfma_f32_16x16x32_bf16(al, bh, acc[nf], 0, 0, 0);
        }
    }

    // z^2 column sums; C-frag: col = lane&15, row = 4*(lane>>4)+j
    #pragma unroll
    for (int nf = 0; nf < 5; ++nf) {
        float part = 0.f;
        #pragma unroll
        for (int j2 = 0; j2 < 4; ++j2) part += acc[nf][j2] * acc[nf][j2];
        part += __shfl_xor(part, 16);
        part += __shfl_xor(part, 32);
        if (q == 0) colsum[wm][wn * 80 + nf * 16 + r16] = part;
    }
    __syncthreads();
    if (t < CPB) {
        float s = 0.f;
        #pragma unroll
        for (int i = 0; i < NSUP; ++i)
            s += colsum[0][t * 20 + i] + colsum[1][t * 20 + i];
        S[batch * NC + cg * CPB + t] = s;
    }
}

// ---- Kernel 3: per-row min-max ----
__global__ __launch_bounds__(64) void k_minmax(const float* __restrict__ S,
                                               float* __restrict__ out) {
    const int b    = blockIdx.x;
    const int lane = threadIdx.x;
    float s  = S[b * NC + lane];
    float mn = s, mx = s;
    #pragma unroll
    for (int off = 32; off > 0; off >>= 1) {
        mn = fminf(mn, __shfl_xor(mn, off, 64));
        mx = fmaxf(mx, __shfl_xor(mx, off, 64));
    }
    out[b * NC + lane] = (s - mn) / (mx - mn);
}

extern "C" void kernel_launch(void* const* d_in, const int* in_sizes, int n_in,
                              void* d_out, int out_size, void* d_ws, size_t ws_size,
                              hipStream_t stream) {
    const float* x    = (const float*)d_in[0];
    const float* high = (const float*)d_in[1];
    float* out = (float*)d_out;

    ushort* Hth = (ushort*)d_ws;                   // 80 frags  * 8192 = 1.31 MB
    ushort* Htl = Hth + 80 * FRAGSZ;               // 1.31 MB
    ushort* Xh  = Htl + 80 * FRAGSZ;               // 256 frags * 8192 = 4.19 MB
    ushort* Xl  = Xh + 256 * FRAGSZ;               // 4.19 MB
    float*  S   = (float*)(Xl + 256 * FRAGSZ);     // 32 KB

    k_prep  <<<256, 256, 0, stream>>>(high, x, Hth, Htl, Xh, Xl);
    k_main  <<<1024, 256, 0, stream>>>(Xh, Xl, Hth, Htl, S);
    k_minmax<<<BB, 64, 0, stream>>>(S, out);
}

// Round 16
// 108.898 us; speedup vs baseline: 1.2772x; 1.2616x over previous
//
#include <hip/hip_runtime.h>

typedef __bf16 v8bf __attribute__((ext_vector_type(8)));
typedef float  v4f  __attribute__((ext_vector_type(4)));

#define D     512
#define NSUP  20
#define NC    64
#define RES   25
#define BB    128
#define LAM   (20.0f/512.0f)
#define KT    32
#define NKT   (D/KT)     // 16
#define CPB   8
#define COLS  160        // CPB*NSUP
#define FRAGSZ (16*D)    // ushorts per fragment-row-group (16 rows x 512 k)

__device__ __forceinline__ ushort bf_hi(float v) {
    uint32_t b = __float_as_uint(v);
    return (ushort)((b + 0x7FFF + ((b >> 16) & 1)) >> 16);   // RNE
}
__device__ __forceinline__ float us2f(ushort u) {
    return __uint_as_float(((uint32_t)u) << 16);
}
// fragment-linear address (in ushorts): row R, k index k
__device__ __forceinline__ int fl_addr(int R, int k) {
    return (R >> 4) * FRAGSZ + (k >> 3) * 128 + (R & 15) * 8 + (k & 7);
}

// ---- Kernel 1 (fused): [blocks 0..127] Gram + dual register-Cholesky +
// ---- panel solves -> fragment-linear Hth/Htl; [blocks 128..255] X hi/lo
// ---- split -> fragment-linear Xh/Xl (pad rows zeroed).
__global__ __launch_bounds__(256) void k_prep(const float* __restrict__ high,
                                              const float* __restrict__ x,
                                              ushort* __restrict__ Hth,
                                              ushort* __restrict__ Htl,
                                              ushort* __restrict__ Xh,
                                              ushort* __restrict__ Xl) {
    const int t = threadIdx.x;

    if (blockIdx.x >= 128) {               // ---- X split, 1 batch per block --
        const int batch = blockIdx.x - 128;
        for (int idx = t; idx < 32 * 64; idx += 256) {
            int r = idx >> 6, o = idx & 63;        // row 0..31, k-octet 0..63
            v8bf hv = (v8bf)(__bf16)0.f, lv = hv;
            if (r < RES) {
                const float* p = &x[(batch * RES + r) * D + (o << 3)];
                float4 v0 = *(const float4*)p, v1 = *(const float4*)(p + 4);
                float vv[8] = {v0.x, v0.y, v0.z, v0.w, v1.x, v1.y, v1.z, v1.w};
                #pragma unroll
                for (int e = 0; e < 8; ++e) {
                    ushort h = bf_hi(vv[e]);
                    ((ushort*)&hv)[e] = h;
                    ((ushort*)&lv)[e] = bf_hi(vv[e] - us2f(h));
                }
            }
            int a = fl_addr(batch * 32 + r, o << 3);
            *(v8bf*)&Xh[a] = hv;
            *(v8bf*)&Xl[a] = lv;
        }
        return;
    }

    const int cls  = blockIdx.x >> 1;
    const int half = blockIdx.x & 1;
    __shared__ float Hc[NSUP * 516];
    __shared__ float Gs[NSUP * NSUP];
    __shared__ float Ls[400], Rs[400], rL[NSUP];

    for (int i = t; i < NSUP * (D / 4); i += 256) {
        int r = i >> 7, c4 = (i & 127) << 2;
        *(float4*)&Hc[r * 516 + c4] = *(const float4*)&high[(cls * NSUP + r) * D + c4];
    }
    __syncthreads();

    // Gram — symmetric half only
    for (int e = t; e < NSUP * NSUP; e += 256) {
        int i = e / NSUP, j = e % NSUP;
        if (i <= j) {
            float s = 0.f;
            for (int k = 0; k < D; k += 4) {
                float4 a = *(float4*)&Hc[i * 516 + k];
                float4 b = *(float4*)&Hc[j * 516 + k];
                s += a.x * b.x + a.y * b.y + a.z * b.z + a.w * b.w;
            }
            Gs[i * NSUP + j] = s;
            Gs[j * NSUP + i] = s;
        }
    }
    __syncthreads();

    // dual in-register Cholesky on wave 0 (lanes 0-19: B, 32-51: C2)
    if (t < 64) {
        const int c  = t & 31;
        const int gp = t >> 5;
        const float dlam = gp ? 2.0f * LAM : LAM;
        float m[NSUP];
        if (c < NSUP) {
            #pragma unroll
            for (int i = 0; i < NSUP; ++i) m[i] = Gs[i * NSUP + c];
            #pragma unroll
            for (int i = 0; i < NSUP; ++i) if (i == c) m[i] += dlam;
        }
        #pragma unroll
        for (int k = 0; k < NSUP; ++k) {
            float piv = __shfl(m[k], k, 32);     // M[k][k] from lane k
            float sq  = sqrtf(piv);
            float rsq = 1.0f / sq;
            float lck = m[k] * rsq;              // L[c][k] via symmetry (c>k)
            if (c == k) {
                m[k] = sq;
                #pragma unroll
                for (int i = k + 1; i < NSUP; ++i) m[i] *= rsq;
            }
            #pragma unroll
            for (int i = k + 1; i < NSUP; ++i) {
                float lik = __shfl(m[i], k, 32); // L[i][k] (post-scale)
                if (c > k) m[i] -= lik * lck;
            }
        }
        if (c < NSUP) {
            float* Lout = gp ? Rs : Ls;
            #pragma unroll
            for (int i = 0; i < NSUP; ++i) if (i >= c) Lout[i * NSUP + c] = m[i];
            if (!gp) rL[c] = 1.0f / m[c];
        }
    }
    __syncthreads();

    // panel solves for this block's 256 columns (H from LDS)
    const int col = half * 256 + t;
    float h[NSUP];
    #pragma unroll
    for (int m = 0; m < NSUP; ++m) h[m] = Hc[m * 516 + col];
    #pragma unroll
    for (int i = 0; i < NSUP; ++i) {            // forward: L z = h
        float s = h[i];
        #pragma unroll
        for (int m = 0; m < i; ++m) s -= Ls[i * NSUP + m] * h[m];
        h[i] = s * rL[i];
    }
    #pragma unroll
    for (int i = NSUP - 1; i >= 0; --i) {       // backward: L^T w = z
        float s = h[i];
        #pragma unroll
        for (int m = i + 1; m < NSUP; ++m) s -= Ls[m * NSUP + i] * h[m];
        h[i] = s * rL[i];
    }
    #pragma unroll
    for (int i = 0; i < NSUP; ++i) {            // ht = R^T w; hi/lo split
        float s = 0.f;
        #pragma unroll
        for (int m = i; m < NSUP; ++m) s += Rs[m * NSUP + i] * h[m];
        ushort hh = bf_hi(s);
        float  rr = s - us2f(hh);
        int a = fl_addr(cls * NSUP + i, col);
        Hth[a] = hh;
        Htl[a] = bf_hi(rr);
    }
}

// ---- Kernel 2: Z = X @ Htilde^T, all-register, manual 2-deep pipeline ------
// Flat 1024-block grid, XCD swizzle as r13. launch_bounds(256,4) -> 128 VGPR:
// all 12 loads of step s+1 in flight while step s's 15 MFMAs run.
__global__ __launch_bounds__(256, 4) void k_main(const ushort* __restrict__ Xh,
                                                 const ushort* __restrict__ Xl,
                                                 const ushort* __restrict__ Hth,
                                                 const ushort* __restrict__ Htl,
                                                 float* __restrict__ S) {
    const int bid = blockIdx.x;
    const int xcd = bid & 7;
    const int j   = bid >> 3;                 // 0..127 within XCD
    const int cg    = (xcd >> 2) * 4 + (j >> 5);       // 0..7
    const int batch = (xcd & 3) * 32 + (j & 31);       // 0..127

    const int t = threadIdx.x, lane = t & 63, wid = t >> 6;
    const int wm = wid >> 1, wn = wid & 1;
    const int r16 = lane & 15, q = lane >> 4;

    __shared__ float colsum[2][COLS];

    v4f acc[5];
    #pragma unroll
    for (int b = 0; b < 5; ++b) acc[b] = (v4f){0.f, 0.f, 0.f, 0.f};

    const int abase = (batch * 2 + wm) * FRAGSZ + lane * 8;
    const ushort* ah_p = Xh + abase;
    const ushort* al_p = Xl + abase;
    const ushort* bh_p[5];
    const ushort* bl_p[5];
    #pragma unroll
    for (int nf = 0; nf < 5; ++nf) {
        int fb = (cg * 10 + wn * 5 + nf) * FRAGSZ + lane * 8;
        bh_p[nf] = Hth + fb;
        bl_p[nf] = Htl + fb;
    }

    // ---- manual 2-deep software pipeline over the 16 K-steps ----
    v8bf cah, cal, cbh[5], cbl[5];    // current stage
    v8bf nah, nal, nbh[5], nbl[5];    // next stage
    cah = *(const v8bf*)(ah_p);
    cal = *(const v8bf*)(al_p);
    #pragma unroll
    for (int nf = 0; nf < 5; ++nf) {
        cbh[nf] = *(const v8bf*)(bh_p[nf]);
        cbl[nf] = *(const v8bf*)(bl_p[nf]);
    }
    #pragma unroll
    for (int s = 0; s < NKT; ++s) {
        if (s + 1 < NKT) {
            const int off = (s + 1) * 512;
            nah = *(const v8bf*)(ah_p + off);
            nal = *(const v8bf*)(al_p + off);
            #pragma unroll
            for (int nf = 0; nf < 5; ++nf) {
                nbh[nf] = *(const v8bf*)(bh_p[nf] + off);
                nbl[nf] = *(const v8bf*)(bl_p[nf] + off);
            }
        }
        #pragma unroll
        for (int nf = 0; nf < 5; ++nf) {
            // 3-pass: drop al*bl (<= 2^-18 relative)
            acc[nf] = __builtin_amdgcn_mfma_f32_16x16x32_bf16(cah, cbh[nf], acc[nf], 0, 0, 0);
            acc[nf] = __builtin_amdgcn_mfma_f32_16x16x32_bf16(cah, cbl[nf], acc[nf], 0, 0, 0);
            acc[nf] = __builtin_amdgcn_mfma_f32_16x16x32_bf16(cal, cbh[nf], acc[nf], 0, 0, 0);
        }
        if (s + 1 < NKT) {
            cah = nah; cal = nal;
            #pragma unroll
            for (int nf = 0; nf < 5; ++nf) { cbh[nf] = nbh[nf]; cbl[nf] = nbl[nf]; }
        }
    }

    // z^2 column sums; C-frag: col = lane&15, row = 4*(lane>>4)+j
    #pragma unroll
    for (int nf = 0; nf < 5; ++nf) {
        float part = 0.f;
        #pragma unroll
        for (int j2 = 0; j2 < 4; ++j2) part += acc[nf][j2] * acc[nf][j2];
        part += __shfl_xor(part, 16);
        part += __shfl_xor(part, 32);
        if (q == 0) colsum[wm][wn * 80 + nf * 16 + r16] = part;
    }
    __syncthreads();
    if (t < CPB) {
        float s = 0.f;
        #pragma unroll
        for (int i = 0; i < NSUP; ++i)
            s += colsum[0][t * 20 + i] + colsum[1][t * 20 + i];
        S[batch * NC + cg * CPB + t] = s;
    }
}

// ---- Kernel 3: per-row min-max ----
__global__ __launch_bounds__(64) void k_minmax(const float* __restrict__ S,
                                               float* __restrict__ out) {
    const int b    = blockIdx.x;
    const int lane = threadIdx.x;
    float s  = S[b * NC + lane];
    float mn = s, mx = s;
    #pragma unroll
    for (int off = 32; off > 0; off >>= 1) {
        mn = fminf(mn, __shfl_xor(mn, off, 64));
        mx = fmaxf(mx, __shfl_xor(mx, off, 64));
    }
    out[b * NC + lane] = (s - mn) / (mx - mn);
}

extern "C" void kernel_launch(void* const* d_in, const int* in_sizes, int n_in,
                              void* d_out, int out_size, void* d_ws, size_t ws_size,
                              hipStream_t stream) {
    const float* x    = (const float*)d_in[0];
    const float* high = (const float*)d_in[1];
    float* out = (float*)d_out;

    ushort* Hth = (ushort*)d_ws;                   // 80 frags  * 8192 = 1.31 MB
    ushort* Htl = Hth + 80 * FRAGSZ;               // 1.31 MB
    ushort* Xh  = Htl + 80 * FRAGSZ;               // 256 frags * 8192 = 4.19 MB
    ushort* Xl  = Xh + 256 * FRAGSZ;               // 4.19 MB
    float*  S   = (float*)(Xl + 256 * FRAGSZ);     // 32 KB

    k_prep  <<<256, 256, 0, stream>>>(high, x, Hth, Htl, Xh, Xl);
    k_main  <<<1024, 256, 0, stream>>>(Xh, Xl, Hth, Htl, S);
    k_minmax<<<BB, 64, 0, stream>>>(S, out);
}